// Round 1
// baseline (2680.899 us; speedup 1.0000x reference)
//
#include <hip/hip_runtime.h>

// SpecialSpmm: out[i] = sum_{e: row_e == i} values[e] * b[col_e]
// N = 100000 rows, E = 1600000 edges, D = 128.
// Inputs (setup_inputs dict order):
//   d_in[0] = values  (E float32)
//   d_in[1] = b       (N*D float32)
//   d_in[2] = indices (2*E int32; indices[0:E]=row, indices[E:2E]=col)
//   d_in[3] = n       (1 int32, == N)
// Output: N*D float32.

#define D_DIM 128
#define CHUNKS (D_DIM / 4)  // 32 float4 chunks per row

__global__ void spmm_atomic_scatter(const float* __restrict__ values,
                                    const float* __restrict__ b,
                                    const int* __restrict__ indices,
                                    float* __restrict__ out,
                                    int E) {
    long long gid = (long long)blockIdx.x * blockDim.x + threadIdx.x;
    long long total = (long long)E * CHUNKS;
    if (gid >= total) return;

    int e = (int)(gid >> 5);   // edge index (gid / 32)
    int c = (int)(gid & 31);   // chunk index within D

    int row = indices[e];
    int col = indices[E + e];
    float v = values[e];

    const float4 bv =
        *reinterpret_cast<const float4*>(b + (long long)col * D_DIM + (c << 2));

    float* o = out + (long long)row * D_DIM + (c << 2);
    atomicAdd(o + 0, v * bv.x);
    atomicAdd(o + 1, v * bv.y);
    atomicAdd(o + 2, v * bv.z);
    atomicAdd(o + 3, v * bv.w);
}

extern "C" void kernel_launch(void* const* d_in, const int* in_sizes, int n_in,
                              void* d_out, int out_size, void* d_ws, size_t ws_size,
                              hipStream_t stream) {
    const float* values = (const float*)d_in[0];
    const float* b      = (const float*)d_in[1];
    const int*   idx    = (const int*)d_in[2];
    float*       out    = (float*)d_out;

    const int E = in_sizes[0];          // 1600000
    // out_size = N * D

    // Harness poisons d_out with 0xAA once; we must zero it every call.
    hipMemsetAsync(d_out, 0, (size_t)out_size * sizeof(float), stream);

    long long total = (long long)E * CHUNKS;
    int block = 256;
    long long grid = (total + block - 1) / block;
    spmm_atomic_scatter<<<(int)grid, block, 0, stream>>>(values, b, idx, out, E);
}

// Round 2
// 334.498 us; speedup vs baseline: 8.0147x; 8.0147x over previous
//
#include <hip/hip_runtime.h>

// SpecialSpmm: out[i] = sum_{e: row_e == i} values[e] * b[col_e]
// N = 100000, E = 1600000, D = 128.
// Strategy: build CSR in workspace (histogram -> scan -> bucket scatter),
// then register-accumulate gather (no float atomics).
//
// d_in[0] = values (E f32), d_in[1] = b (N*D f32),
// d_in[2] = indices (2*E i32: rows then cols), d_in[3] = n (1 i32).

#define D_DIM   128
#define SCAN_B  1024

// ---------------- pass 1: histogram of rows ----------------
__global__ void hist_rows(const int* __restrict__ indices, int* __restrict__ cnt, int E) {
    int stride = gridDim.x * blockDim.x;
    for (int e = blockIdx.x * blockDim.x + threadIdx.x; e < E; e += stride)
        atomicAdd(&cnt[indices[e]], 1);
}

// ---------------- pass 2: exclusive scan (3-kernel) ----------------
__global__ void scan_block(const int* __restrict__ cnt, int* __restrict__ off,
                           int* __restrict__ partials, int n) {
    __shared__ int s[SCAN_B];
    int tid = threadIdx.x;
    int i = blockIdx.x * SCAN_B + tid;
    int v = (i < n) ? cnt[i] : 0;
    s[tid] = v;
    __syncthreads();
    for (int ofs = 1; ofs < SCAN_B; ofs <<= 1) {
        int t = (tid >= ofs) ? s[tid - ofs] : 0;
        __syncthreads();
        s[tid] += t;
        __syncthreads();
    }
    if (i < n) off[i] = s[tid] - v;          // exclusive within block
    if (tid == SCAN_B - 1) partials[blockIdx.x] = s[SCAN_B - 1];
}

__global__ void scan_partials(int* __restrict__ partials, int nb) {
    if (threadIdx.x == 0 && blockIdx.x == 0) {
        int run = 0;
        for (int i = 0; i < nb; ++i) { int t = partials[i]; partials[i] = run; run += t; }
    }
}

__global__ void scan_add(int* __restrict__ off, int* __restrict__ cursor,
                         const int* __restrict__ partials, int n, int E) {
    int i = blockIdx.x * SCAN_B + threadIdx.x;
    if (i < n) {
        int v = off[i] + partials[blockIdx.x];
        off[i] = v;
        cursor[i] = v;
    }
    if (i == 0) off[n] = E;
}

// ---------------- pass 3: bucket edges by row ----------------
__global__ void scatter_edges(const int* __restrict__ indices, const float* __restrict__ values,
                              int* __restrict__ cursor, int2* __restrict__ cv, int E) {
    int stride = gridDim.x * blockDim.x;
    for (int e = blockIdx.x * blockDim.x + threadIdx.x; e < E; e += stride) {
        int row = indices[e];
        int col = indices[E + e];
        float v = values[e];
        int pos = atomicAdd(&cursor[row], 1);
        cv[pos] = make_int2(col, __float_as_int(v));
    }
}

// ---------------- pass 4: per-row register gather ----------------
// 32 lanes per row (float4 each), 8 rows per 256-thread block.
__global__ void spmm_gather(const float* __restrict__ b, const int* __restrict__ off,
                            const int2* __restrict__ cv, float* __restrict__ out, int N) {
    int lane = threadIdx.x & 31;
    int row  = blockIdx.x * 8 + (threadIdx.x >> 5);
    if (row >= N) return;

    int s = off[row];
    int e = off[row + 1];

    float4 acc = make_float4(0.f, 0.f, 0.f, 0.f);
    int i = s;
    for (; i + 1 < e; i += 2) {
        int2 p0 = cv[i];
        int2 p1 = cv[i + 1];
        float v0 = __int_as_float(p0.y);
        float v1 = __int_as_float(p1.y);
        const float4 b0 = *reinterpret_cast<const float4*>(b + p0.x * D_DIM + (lane << 2));
        const float4 b1 = *reinterpret_cast<const float4*>(b + p1.x * D_DIM + (lane << 2));
        acc.x += v0 * b0.x; acc.y += v0 * b0.y; acc.z += v0 * b0.z; acc.w += v0 * b0.w;
        acc.x += v1 * b1.x; acc.y += v1 * b1.y; acc.z += v1 * b1.z; acc.w += v1 * b1.w;
    }
    if (i < e) {
        int2 p0 = cv[i];
        float v0 = __int_as_float(p0.y);
        const float4 b0 = *reinterpret_cast<const float4*>(b + p0.x * D_DIM + (lane << 2));
        acc.x += v0 * b0.x; acc.y += v0 * b0.y; acc.z += v0 * b0.z; acc.w += v0 * b0.w;
    }
    *reinterpret_cast<float4*>(out + row * D_DIM + (lane << 2)) = acc;
}

// ---------------- fallback (round-1 atomic scatter) ----------------
__global__ void spmm_atomic_scatter(const float* __restrict__ values,
                                    const float* __restrict__ b,
                                    const int* __restrict__ indices,
                                    float* __restrict__ out, int E) {
    long long gid = (long long)blockIdx.x * blockDim.x + threadIdx.x;
    long long total = (long long)E * 32;
    if (gid >= total) return;
    int e = (int)(gid >> 5);
    int c = (int)(gid & 31);
    int row = indices[e];
    int col = indices[E + e];
    float v = values[e];
    const float4 bv = *reinterpret_cast<const float4*>(b + (long long)col * D_DIM + (c << 2));
    float* o = out + (long long)row * D_DIM + (c << 2);
    atomicAdd(o + 0, v * bv.x);
    atomicAdd(o + 1, v * bv.y);
    atomicAdd(o + 2, v * bv.z);
    atomicAdd(o + 3, v * bv.w);
}

extern "C" void kernel_launch(void* const* d_in, const int* in_sizes, int n_in,
                              void* d_out, int out_size, void* d_ws, size_t ws_size,
                              hipStream_t stream) {
    const float* values = (const float*)d_in[0];
    const float* b      = (const float*)d_in[1];
    const int*   idx    = (const int*)d_in[2];
    float*       out    = (float*)d_out;

    const int E = in_sizes[0];
    const int N = out_size / D_DIM;
    const int nb = (N + SCAN_B - 1) / SCAN_B;

    // Workspace layout (ints):
    //   off:      N+1
    //   cursor:   N
    //   partials: nb (pad 1024)
    //   cv:       2*E  (int2 per edge)
    size_t need = ((size_t)(N + 1) + N + 1024 + 2 * (size_t)E) * sizeof(int);
    if (ws_size < need) {
        // Fallback: atomic scatter (correct, slower).
        hipMemsetAsync(d_out, 0, (size_t)out_size * sizeof(float), stream);
        long long total = (long long)E * 32;
        int block = 256;
        long long grid = (total + block - 1) / block;
        spmm_atomic_scatter<<<(int)grid, block, 0, stream>>>(values, b, idx, out, E);
        return;
    }

    int*  off      = (int*)d_ws;
    int*  cursor   = off + (N + 1);
    int*  partials = cursor + N;
    int2* cv       = (int2*)(partials + 1024);

    // 1. zero counts (use cursor buffer to hold counts first)
    hipMemsetAsync(cursor, 0, (size_t)N * sizeof(int), stream);
    // 2. histogram
    hist_rows<<<2048, 256, 0, stream>>>(idx, cursor, E);
    // 3. scan counts -> off (exclusive), copy to cursor
    scan_block<<<nb, SCAN_B, 0, stream>>>(cursor, off, partials, N);
    scan_partials<<<1, 64, 0, stream>>>(partials, nb);
    scan_add<<<nb, SCAN_B, 0, stream>>>(off, cursor, partials, N, E);
    // 4. bucket edges by row
    scatter_edges<<<2048, 256, 0, stream>>>(idx, values, cursor, cv, E);
    // 5. gather: 8 rows per 256-thread block
    spmm_gather<<<(N + 7) / 8, 256, 0, stream>>>(b, off, cv, out, N);
}